// Round 1
// baseline (409.711 us; speedup 1.0000x reference)
//
#include <hip/hip_runtime.h>

// MHAttention: x(2,32,512,512) fp32; Q/K/V proj + 8-head attention (L=512, D=64).
// Pipeline: conv_x (fp32->bf16), prep_w (W^T bf16), gemm_qkv (bf16 MFMA, bias fused),
// attn (flash-style, online softmax, fp32 out).
// Workspace layout (u16 elements): xb[16777216] | WT[786432] | Q|K|V [3*16777216]
// => ~130 MB required in d_ws.

typedef unsigned short u16;
typedef unsigned int u32;
typedef __bf16 bf16x8 __attribute__((ext_vector_type(8)));
typedef float f32x4 __attribute__((ext_vector_type(4)));

#define LOG2E 1.44269504088896340736f

static __device__ __forceinline__ u16 f2bf(float f) {
  // RNE truncate fp32->bf16 (no NaN handling; inputs are finite normals)
  u32 x = __float_as_uint(f);
  x += 0x7fffu + ((x >> 16) & 1u);
  return (u16)(x >> 16);
}

// ---------------- stage 0a: x fp32 -> bf16 ----------------
__global__ __launch_bounds__(256) void conv_x(const float* __restrict__ x,
                                              u16* __restrict__ xb) {
  const u32 i = (blockIdx.x * 256u + threadIdx.x) * 8u;
  const float4 a = *(const float4*)(x + i);
  const float4 b = *(const float4*)(x + i + 4);
  union { u16 r[8]; uint4 v; } u;
  u.r[0] = f2bf(a.x); u.r[1] = f2bf(a.y); u.r[2] = f2bf(a.z); u.r[3] = f2bf(a.w);
  u.r[4] = f2bf(b.x); u.r[5] = f2bf(b.y); u.r[6] = f2bf(b.z); u.r[7] = f2bf(b.w);
  *(uint4*)(xb + i) = u.v;
}

// ---------------- stage 0b: W (k,n) fp32 -> WT (n,k) bf16, 3 matrices ----------------
__global__ __launch_bounds__(256) void prep_w(const float* __restrict__ Wq,
                                              const float* __restrict__ Wk,
                                              const float* __restrict__ Wv,
                                              u16* __restrict__ WT) {
  __shared__ float t[32][33];
  const int z = blockIdx.z;
  const float* W = (z == 0) ? Wq : ((z == 1) ? Wk : Wv);
  u16* dst = WT + z * 262144;
  const int k0 = blockIdx.x * 32, n0 = blockIdx.y * 32;
  const int tx = threadIdx.x & 31, ty = threadIdx.x >> 5;  // 32x8
#pragma unroll
  for (int i = 0; i < 32; i += 8)
    t[ty + i][tx] = W[(size_t)(k0 + ty + i) * 512 + n0 + tx];
  __syncthreads();
#pragma unroll
  for (int i = 0; i < 32; i += 8)
    dst[(size_t)(n0 + ty + i) * 512 + k0 + tx] = f2bf(t[tx][ty + i]);
}

// ---------------- stage 1: QKV = x @ W + b  (bf16 MFMA GEMM) ----------------
// grid (256 mblocks, 4 nblocks, 3 qkv), 256 threads (4 waves, 2x2 of 64x64).
__global__ __launch_bounds__(256) void gemm_qkv(const u16* __restrict__ xb,
                                                const u16* __restrict__ WT,
                                                const float* __restrict__ bq,
                                                const float* __restrict__ bk,
                                                const float* __restrict__ bv,
                                                u16* __restrict__ qkv) {
  constexpr int LDT = 40;  // 80B rows: 16B-aligned, 20-bank stride -> 2-way (free)
  __shared__ u16 sA[128 * LDT];
  __shared__ u16 sB[128 * LDT];
  const int z = blockIdx.z;
  const u16* Bg = WT + z * 262144;
  const float* bias = (z == 0) ? bq : ((z == 1) ? bk : bv);
  u16* out = qkv + (size_t)z * 16777216u;
  const int tid = threadIdx.x;
  const int lane = tid & 63;
  const int w = tid >> 6;
  const int wy = w >> 1, wx = w & 1;
  const int m15 = lane & 15, g = lane >> 4;
  const int mbase = blockIdx.x * 128;
  const int nbase = blockIdx.y * 128;

  // staging: 512 chunks (16B) per tile, 2 per thread, same row
  const int srow = tid >> 1;
  const int sg8 = (tid & 1) * 16;
  const u16* Ap = xb + (size_t)(mbase + srow) * 512 + sg8;
  const u16* Bp = Bg + (size_t)(nbase + srow) * 512 + sg8;
  u16* sAw = &sA[srow * LDT + sg8];
  u16* sBw = &sB[srow * LDT + sg8];

  f32x4 acc[4][4] = {};

  for (int kt = 0; kt < 16; ++kt) {
    const int k0 = kt * 32;
    const uint4 a0 = *(const uint4*)(Ap + k0);
    const uint4 a1 = *(const uint4*)(Ap + k0 + 8);
    const uint4 b0 = *(const uint4*)(Bp + k0);
    const uint4 b1 = *(const uint4*)(Bp + k0 + 8);
    __syncthreads();
    *(uint4*)sAw = a0;
    *(uint4*)(sAw + 8) = a1;
    *(uint4*)sBw = b0;
    *(uint4*)(sBw + 8) = b1;
    __syncthreads();
    bf16x8 af[4], bfr[4];
#pragma unroll
    for (int t = 0; t < 4; ++t)
      af[t] = *(const bf16x8*)&sA[(wy * 64 + t * 16 + m15) * LDT + g * 8];
#pragma unroll
    for (int t = 0; t < 4; ++t)
      bfr[t] = *(const bf16x8*)&sB[(wx * 64 + t * 16 + m15) * LDT + g * 8];
#pragma unroll
    for (int rt = 0; rt < 4; ++rt)
#pragma unroll
      for (int ct = 0; ct < 4; ++ct)
        acc[rt][ct] =
            __builtin_amdgcn_mfma_f32_16x16x32_bf16(af[rt], bfr[ct], acc[rt][ct], 0, 0, 0);
  }

  // epilogue: + bias, cvt bf16, store (C/D: col=lane&15, row=quad*4+reg)
#pragma unroll
  for (int ct = 0; ct < 4; ++ct) {
    const int col = nbase + wx * 64 + ct * 16 + m15;
    const float bb = bias[col];
#pragma unroll
    for (int rt = 0; rt < 4; ++rt) {
      const int row0 = mbase + wy * 64 + rt * 16 + g * 4;
#pragma unroll
      for (int r = 0; r < 4; ++r)
        out[(size_t)(row0 + r) * 512 + col] = f2bf(acc[rt][ct][r] + bb);
    }
  }
}

// ---------------- stage 2: flash attention per (q-tile=128, head, bm) ----------------
// 4 waves, each 32 q-rows (2 row-tiles). j-tiles of 32. exp2-domain softmax.
__global__ __launch_bounds__(256) void attn(const u16* __restrict__ Q,
                                            const u16* __restrict__ K,
                                            const u16* __restrict__ V,
                                            float* __restrict__ out) {
  constexpr float SC = 0.125f * LOG2E;  // 1/sqrt(64) folded with log2(e)
  __shared__ u16 sK[32 * 72];      // K-tile row j, stride 72 (144B: aligned, 2-way)
  __shared__ u16 sVT[64 * 40];     // V^T tile row d, stride 40
  __shared__ u16 sP[4][32 * 40];   // per-wave P scratch (C-layout -> A-layout relay)
  const int tid = threadIdx.x;
  const int lane = tid & 63;
  const int w = tid >> 6;
  const int m15 = lane & 15, g = lane >> 4;
  const int qt = blockIdx.x, h = blockIdx.y, bm = blockIdx.z;
  const size_t rb = (size_t)bm * 512;
  const int q0 = qt * 128 + w * 32;

  // Q fragments (A-layout), resident for whole kernel
  bf16x8 qf[2][2];
#pragma unroll
  for (int rt = 0; rt < 2; ++rt)
#pragma unroll
    for (int kc = 0; kc < 2; ++kc)
      qf[rt][kc] =
          *(const bf16x8*)(Q + (rb + q0 + rt * 16 + m15) * 512 + h * 64 + kc * 32 + g * 8);

  f32x4 acc[2][4] = {};
  f32x4 mo[2], li[2];
  const f32x4 NEGBIG = {-1e30f, -1e30f, -1e30f, -1e30f};
  const f32x4 ZERO = {0.f, 0.f, 0.f, 0.f};
  mo[0] = NEGBIG; mo[1] = NEGBIG;
  li[0] = ZERO;   li[1] = ZERO;

  const int krow = tid >> 3, kc8 = (tid & 7) * 8;  // K staging: 1 chunk/thread
  const int vd = tid >> 2, vj = (tid & 3) * 8;     // V^T staging: 8 scalars/thread
  const u16* Kb = K + rb * 512 + h * 64;
  const u16* Vb = V + rb * 512 + h * 64;

  for (int jt = 0; jt < 16; ++jt) {
    const int j0 = jt * 32;
    // prefetch into regs before barrier
    const uint4 kv = *(const uint4*)(Kb + (size_t)(j0 + krow) * 512 + kc8);
    u16 vv[8];
#pragma unroll
    for (int t = 0; t < 8; ++t)
      vv[t] = Vb[(size_t)(j0 + vj + t) * 512 + vd];
    __syncthreads();  // all waves done reading previous sK/sVT
    *(uint4*)&sK[krow * 72 + kc8] = kv;
#pragma unroll
    for (int t = 0; t < 8; ++t)
      sVT[vd * 40 + vj + t] = vv[t];  // transpose on the way in
    __syncthreads();

    // S = Q K^T  (B-layout from sK: n=kj, k=d)
    bf16x8 kf[2][2];
#pragma unroll
    for (int ct = 0; ct < 2; ++ct)
#pragma unroll
      for (int kc = 0; kc < 2; ++kc)
        kf[ct][kc] = *(const bf16x8*)&sK[(ct * 16 + m15) * 72 + kc * 32 + g * 8];

    f32x4 s[2][2] = {};
#pragma unroll
    for (int rt = 0; rt < 2; ++rt)
#pragma unroll
      for (int ct = 0; ct < 2; ++ct) {
        s[rt][ct] =
            __builtin_amdgcn_mfma_f32_16x16x32_bf16(qf[rt][0], kf[ct][0], s[rt][ct], 0, 0, 0);
        s[rt][ct] =
            __builtin_amdgcn_mfma_f32_16x16x32_bf16(qf[rt][1], kf[ct][1], s[rt][ct], 0, 0, 0);
      }

    // online softmax (exp2 domain); rows live in reg r, 16 lanes of group g share a row
#pragma unroll
    for (int rt = 0; rt < 2; ++rt) {
      f32x4 s0 = s[rt][0] * SC;
      f32x4 s1 = s[rt][1] * SC;
      f32x4 mx;
#pragma unroll
      for (int r = 0; r < 4; ++r) mx[r] = fmaxf(s0[r], s1[r]);
#pragma unroll
      for (int d = 1; d < 16; d <<= 1)
#pragma unroll
        for (int r = 0; r < 4; ++r)
          mx[r] = fmaxf(mx[r], __shfl_xor(mx[r], d));
      f32x4 mn, al, p0, p1;
#pragma unroll
      for (int r = 0; r < 4; ++r) {
        mn[r] = fmaxf(mo[rt][r], mx[r]);
        al[r] = exp2f(mo[rt][r] - mn[r]);
        p0[r] = exp2f(s0[r] - mn[r]);
        p1[r] = exp2f(s1[r] - mn[r]);
      }
      mo[rt] = mn;
      f32x4 rs = p0 + p1;
#pragma unroll
      for (int d = 1; d < 16; d <<= 1)
#pragma unroll
        for (int r = 0; r < 4; ++r)
          rs[r] += __shfl_xor(rs[r], d);
      li[rt] = li[rt] * al + rs;
#pragma unroll
      for (int nt = 0; nt < 4; ++nt) acc[rt][nt] *= al;
      // P: C-layout -> row-major LDS (per-wave scratch, no barrier needed)
#pragma unroll
      for (int r = 0; r < 4; ++r) {
        sP[w][(rt * 16 + g * 4 + r) * 40 + m15] = f2bf(p0[r]);
        sP[w][(rt * 16 + g * 4 + r) * 40 + 16 + m15] = f2bf(p1[r]);
      }
    }

    // O += P V   (P via A-layout from sP; V via B-layout from sVT)
    bf16x8 pa[2];
#pragma unroll
    for (int rt = 0; rt < 2; ++rt)
      pa[rt] = *(const bf16x8*)&sP[w][(rt * 16 + m15) * 40 + g * 8];
#pragma unroll
    for (int nt = 0; nt < 4; ++nt) {
      const bf16x8 vf = *(const bf16x8*)&sVT[(nt * 16 + m15) * 40 + g * 8];
#pragma unroll
      for (int rt = 0; rt < 2; ++rt)
        acc[rt][nt] = __builtin_amdgcn_mfma_f32_16x16x32_bf16(pa[rt], vf, acc[rt][nt], 0, 0, 0);
    }
  }

  // epilogue: normalize by li, store fp32 (coalesced 64B per 16 lanes)
#pragma unroll
  for (int rt = 0; rt < 2; ++rt) {
    f32x4 inv;
#pragma unroll
    for (int r = 0; r < 4; ++r) inv[r] = 1.0f / li[rt][r];
#pragma unroll
    for (int nt = 0; nt < 4; ++nt)
#pragma unroll
      for (int r = 0; r < 4; ++r)
        out[(rb + q0 + rt * 16 + g * 4 + r) * 512 + h * 64 + nt * 16 + m15] =
            acc[rt][nt][r] * inv[r];
  }
}

extern "C" void kernel_launch(void* const* d_in, const int* in_sizes, int n_in,
                              void* d_out, int out_size, void* d_ws, size_t ws_size,
                              hipStream_t stream) {
  const float* x = (const float*)d_in[0];
  const float* Wq = (const float*)d_in[1];
  const float* bq = (const float*)d_in[2];
  const float* Wk = (const float*)d_in[3];
  const float* bk = (const float*)d_in[4];
  const float* Wv = (const float*)d_in[5];
  const float* bv = (const float*)d_in[6];
  float* out = (float*)d_out;

  u16* ws = (u16*)d_ws;
  u16* xb = ws;                      // 16,777,216
  u16* WT = ws + 16777216;           // 786,432
  u16* qkv = ws + 17563648;          // 3 x 16,777,216 (Q,K,V)

  conv_x<<<8192, 256, 0, stream>>>(x, xb);
  prep_w<<<dim3(16, 16, 3), 256, 0, stream>>>(Wq, Wk, Wv, WT);
  gemm_qkv<<<dim3(256, 4, 3), 256, 0, stream>>>(xb, WT, bq, bk, bv, qkv);
  attn<<<dim3(4, 8, 64), 256, 0, stream>>>(qkv, qkv + 16777216, qkv + 2 * 16777216, out);
}